// Round 7
// baseline (320.332 us; speedup 1.0000x reference)
//
#include <hip/hip_runtime.h>

// Problem geometry (fixed by the reference): B=8, H=1024, W=1024, periodic.
#define WMASK 1023
#define LOG2W 10
#define HW (1024 * 1024)

#define EPS 1e-6f
#define DT 1e-2f

// Output tile 64x16, 256 threads, 1 float4 of output per thread.
// Single tile per block (R6's lean body, R0/R4's occupancy): raw fields staged
// by global_load_lds DMA (no VGPR round-trip), all LDS reads dense f4,
// x-neighbor exchange via shuffles. LDS 24,896 B -> 6 blocks/CU (24 waves);
// staging latency is covered by other resident blocks (implicit overlap),
// not by an explicit double buffer (R6 showed that costs more TLP than it buys).
#define TX 64
#define TY 16

// Raw tile, f4-task-indexed, LDS float offset of task t is exactly 4t:
//   cv  tasks [0,360):   x [x0-4,x0+67] (18 chunks, row stride 72), y [-2,+17]
//   ci  tasks [360,720)
//   eta tasks [720,1044): y [-1,+16] (18 rows)
#define RST 72
#define NTASK 1044
#define RAWF (NTASK * 4)     // 4176 floats = 16704 B
#define CI_OFF 1440
#define ETA_OFF 2880
// dF tiles: interior only, 16 chunks x 16 rows, dense stride 64 (8192 B).
#define SST 64

typedef float f4 __attribute__((ext_vector_type(4)));
typedef unsigned int u32;

__device__ __forceinline__ float scal(const float* __restrict__ p) {
    return fabsf(p[0]) + 0.001f;
}
__device__ __forceinline__ float clip01(float v) {
    return fminf(fmaxf(v, 0.0f), 1.0f);
}
// log2 of clamped arg; caller folds ln2 into the kBT scalar (kl).
__device__ __forceinline__ float lg2m(float m) {
    return __log2f(fmaxf(m, EPS));   // jnp.log(where(m<eps,eps,m)) == ln2*log2(max(m,eps))
}

// Barrier waiting only this wave's LDS ops (no vmcnt drain of the nt stores).
__device__ __forceinline__ void lgkm_barrier() {
    asm volatile("s_waitcnt lgkmcnt(0)" ::: "memory");
    __builtin_amdgcn_s_barrier();
}
// Staging barrier: own DMA loads drained, then sync.
__device__ __forceinline__ void vm_barrier() {
    asm volatile("s_waitcnt vmcnt(0)" ::: "memory");
    __builtin_amdgcn_s_barrier();
}

// 16B global -> LDS DMA. LDS dest is wave-uniform base + lane*16 (our task
// layout is linear in tid, satisfying this).
__device__ __forceinline__ void gld16(const float* g, float* l) {
    __builtin_amdgcn_global_load_lds(
        (const __attribute__((address_space(1))) u32*)g,
        (__attribute__((address_space(3))) u32*)l, 16, 0, 0);
}

__global__ __launch_bounds__(256, 6) void irr_fused(
    const float* __restrict__ cv,
    const float* __restrict__ ci,
    const float* __restrict__ eta,
    const float* __restrict__ p_ev,
    const float* __restrict__ p_ei,
    const float* __restrict__ p_kbt,
    const float* __restrict__ p_kv,
    const float* __restrict__ p_ki,
    const float* __restrict__ p_ke,
    const float* __restrict__ p_dv,
    const float* __restrict__ p_di,
    const float* __restrict__ p_L,
    float* __restrict__ cv_new,
    float* __restrict__ ci_new,
    float* __restrict__ eta_new)
{
    __shared__ __attribute__((aligned(16))) float sraw[RAWF];
    __shared__ __attribute__((aligned(16))) float sdv[16][SST];
    __shared__ __attribute__((aligned(16))) float sdi[16][SST];

    const int tid = threadIdx.x;
    const int x0 = blockIdx.x * TX;
    const int y0 = blockIdx.y * TY;
    const int bbase = blockIdx.z * HW;

    // ---- Stage raw fields via DMA (5 issues/thread, zero staging VGPRs) ----
    #pragma unroll
    for (int i = 0; i < 5; ++i) {
        const int t = tid + (i << 8);
        if (i < 4 || tid < NTASK - 1024) {
            const float* src; int r, ry0;
            if (t < 360)      { src = cv;  r = t;       ry0 = y0 - 2; }
            else if (t < 720) { src = ci;  r = t - 360; ry0 = y0 - 2; }
            else              { src = eta; r = t - 720; ry0 = y0 - 1; }
            const int cx = r % 18;
            const int cy = r / 18;
            const int gx = (x0 - 4 + (cx << 2)) & WMASK;   // 4-aligned, no row-cross
            const int gy = (ry0 + cy) & WMASK;
            gld16(src + bbase + (gy << LOG2W) + gx, &sraw[t << 2]);
        }
    }

    const float energy_v = scal(p_ev);
    const float energy_i = scal(p_ei);
    const float kBT      = scal(p_kbt);
    const float kappa_v  = scal(p_kv);
    const float kappa_i  = scal(p_ki);
    const float kappa_e  = scal(p_ke);
    const float diff_v   = scal(p_dv);
    const float diff_i   = scal(p_di);
    const float L        = scal(p_L);
    const float kl   = kBT * 0.69314718056f;   // kBT*ln2: folds log2->ln
    const float dtl  = DT * L;
    const float dtrv = DT * diff_v / kBT;      // DT * mv / cv
    const float dtri = DT * diff_i / kBT;

    vm_barrier();    // own DMA drained; other resident blocks cover the wait

    const int k  = tid & 15;          // chunk col; global x = x0 + 4k
    const int ey = tid >> 4;          // row within tile
    const int rx = (k << 2) + 4;      // raw float col of x0+4k
    const int c  = k << 2;

    // ---- Phase 1: straight-line, 1 interior chunk per thread.
    //      All f4 reads dense per wave; x-neighbor scalars via shuffle. ----
    const f4 cC = *(const f4*)&sraw[(ey + 2) * RST + rx];
    const f4 cU = *(const f4*)&sraw[(ey + 1) * RST + rx];
    const f4 cD = *(const f4*)&sraw[(ey + 3) * RST + rx];
    const f4 iC = *(const f4*)&sraw[CI_OFF + (ey + 2) * RST + rx];
    const f4 iU = *(const f4*)&sraw[CI_OFF + (ey + 1) * RST + rx];
    const f4 iD = *(const f4*)&sraw[CI_OFF + (ey + 3) * RST + rx];
    const f4 eC = *(const f4*)&sraw[ETA_OFF + (ey + 1) * RST + rx];
    const f4 eU = *(const f4*)&sraw[ETA_OFF + (ey)     * RST + rx];
    const f4 eD = *(const f4*)&sraw[ETA_OFF + (ey + 2) * RST + rx];

    float cL = __shfl_up(cC[3], 1), cR = __shfl_down(cC[0], 1);
    float iL = __shfl_up(iC[3], 1), iR = __shfl_down(iC[0], 1);
    float eL = __shfl_up(eC[3], 1), eR = __shfl_down(eC[0], 1);
    if (k == 0) {        // no left lane in-row: read col 3 (x0-1)
        cL = sraw[(ey + 2) * RST + 3];
        iL = sraw[CI_OFF + (ey + 2) * RST + 3];
        eL = sraw[ETA_OFF + (ey + 1) * RST + 3];
    }
    if (k == 15) {       // col 68 (x0+64)
        cR = sraw[(ey + 2) * RST + 68];
        iR = sraw[CI_OFF + (ey + 2) * RST + 68];
        eR = sraw[ETA_OFF + (ey + 1) * RST + 68];
    }

    f4 dv, di, en;
    #pragma unroll
    for (int j = 0; j < 4; ++j) {
        const float c0 = cC[j];
        const float i0 = iC[j];
        const float e0 = eC[j];
        const float cl = (j == 0) ? cL : cC[j - 1];
        const float cr = (j == 3) ? cR : cC[j + 1];
        const float il = (j == 0) ? iL : iC[j - 1];
        const float ir = (j == 3) ? iR : iC[j + 1];
        const float el = (j == 0) ? eL : eC[j - 1];
        const float er = (j == 3) ? eR : eC[j + 1];

        const float lap_cv  = cl + cr + cU[j] + cD[j] - 4.0f * c0;
        const float lap_ci  = il + ir + iU[j] + iD[j] - 4.0f * i0;
        const float lap_eta = el + er + eU[j] + eD[j] - 4.0f * e0;

        const float h  = (e0 - 1.0f) * (e0 - 1.0f);
        const float jj = e0 * e0;
        const float cs = 1.0f - c0 - i0;
        const float lgv = lg2m(c0);
        const float lgi = lg2m(i0);
        const float lgs = lg2m(cs);

        dv[j] = h * (energy_v + kl * (lgv - lgs)) + jj * (2.0f * (c0 - 1.0f))
              - kappa_v * lap_cv;
        di[j] = h * (energy_i + kl * (lgi - lgs)) + jj * (2.0f * i0)
              - kappa_i * lap_ci;

        const float fs = energy_v * c0 + energy_i * i0
                       + kl * (c0 * lgv + i0 * lgi + cs * lgs);
        const float fv = (c0 - 1.0f) * (c0 - 1.0f) + i0 * i0;
        const float dF_deta = fs * 2.0f * (e0 - 1.0f) + fv * 2.0f * e0
                            - kappa_e * lap_eta;   // N_PARAM == 1.0
        en[j] = clip01(fmaf(-dtl, dF_deta, e0));
    }

    *(f4*)&sdv[ey][c] = dv;
    *(f4*)&sdi[ey][c] = di;

    // x-halo dF via shuffle (lane+-1's dv/di registers)
    float vL = __shfl_up(dv[3], 1), vR = __shfl_down(dv[0], 1);
    float wL = __shfl_up(di[3], 1), wR = __shfl_down(di[0], 1);

    lgkm_barrier();   // sdv/sdi visible to all waves

    // ---- Phase 2: centers from registers; y-halo dF from dense LDS;
    //      tile-edge halo recomputed locally from the raw LDS. ----
    auto evalpt = [&](int cr, int cc, int er) -> float2 {
        const float c0 = sraw[cr * RST + cc];
        const float lap_cv = sraw[cr * RST + cc - 1]
                           + sraw[cr * RST + cc + 1]
                           + sraw[(cr - 1) * RST + cc]
                           + sraw[(cr + 1) * RST + cc] - 4.0f * c0;
        const float i0 = sraw[CI_OFF + cr * RST + cc];
        const float lap_ci = sraw[CI_OFF + cr * RST + cc - 1]
                           + sraw[CI_OFF + cr * RST + cc + 1]
                           + sraw[CI_OFF + (cr - 1) * RST + cc]
                           + sraw[CI_OFF + (cr + 1) * RST + cc] - 4.0f * i0;
        const float e0 = sraw[ETA_OFF + er * RST + cc];
        const float h  = (e0 - 1.0f) * (e0 - 1.0f);
        const float jj = e0 * e0;
        const float cs = 1.0f - c0 - i0;
        const float lgv = lg2m(c0);
        const float lgi = lg2m(i0);
        const float lgs = lg2m(cs);
        const float dvx = h * (energy_v + kl * (lgv - lgs))
                        + jj * (2.0f * (c0 - 1.0f)) - kappa_v * lap_cv;
        const float dix = h * (energy_i + kl * (lgi - lgs))
                        + jj * (2.0f * i0) - kappa_i * lap_ci;
        return make_float2(dvx, dix);
    };

    if (k == 0) {
        const float2 r = evalpt(ey + 2, 3, ey + 1);      // dF(x0-1)
        vL = r.x; wL = r.y;
    }
    if (k == 15) {
        const float2 r = evalpt(ey + 2, 68, ey + 1);     // dF(x0+64)
        vR = r.x; wR = r.y;
    }

    f4 vU, wU, vD, wD;
    if (ey == 0) {
        #pragma unroll
        for (int j = 0; j < 4; ++j) {                    // dF(y0-1)
            const float2 r = evalpt(1, rx + j, 0);
            vU[j] = r.x; wU[j] = r.y;
        }
    } else {
        vU = *(const f4*)&sdv[ey - 1][c];
        wU = *(const f4*)&sdi[ey - 1][c];
    }
    if (ey == 15) {
        #pragma unroll
        for (int j = 0; j < 4; ++j) {                    // dF(y0+16)
            const float2 r = evalpt(18, rx + j, 17);
            vD[j] = r.x; wD[j] = r.y;
        }
    } else {
        vD = *(const f4*)&sdv[ey + 1][c];
        wD = *(const f4*)&sdi[ey + 1][c];
    }

    const int gidx = bbase + ((y0 + ey) << LOG2W) + (x0 + c);  // interior
    f4 outv, outi;
    #pragma unroll
    for (int j = 0; j < 4; ++j) {
        const float lv = ((j == 0) ? vL : dv[j - 1]) + ((j == 3) ? vR : dv[j + 1])
                       + vU[j] + vD[j] - 4.0f * dv[j];
        const float li = ((j == 0) ? wL : di[j - 1]) + ((j == 3) ? wR : di[j + 1])
                       + wU[j] + wD[j] - 4.0f * di[j];
        outv[j] = clip01(fmaf(dtrv * cC[j], lv, cC[j]));
        outi[j] = clip01(fmaf(dtri * iC[j], li, iC[j]));
    }
    __builtin_nontemporal_store(en,   (f4*)(eta_new + gidx));
    __builtin_nontemporal_store(outv, (f4*)(cv_new + gidx));
    __builtin_nontemporal_store(outi, (f4*)(ci_new + gidx));
}

extern "C" void kernel_launch(void* const* d_in, const int* in_sizes, int n_in,
                              void* d_out, int out_size, void* d_ws, size_t ws_size,
                              hipStream_t stream) {
    // Input order: cv, ci, eta, energy_v0, energy_i0, kBT0, kappa_v0, kappa_i0,
    //              kappa_eta0, diff_v0, diff_i0, L0  — all float32 per reference.
    const float* cv  = (const float*)d_in[0];
    const float* ci  = (const float*)d_in[1];
    const float* eta = (const float*)d_in[2];
    const float* p_ev  = (const float*)d_in[3];
    const float* p_ei  = (const float*)d_in[4];
    const float* p_kbt = (const float*)d_in[5];
    const float* p_kv  = (const float*)d_in[6];
    const float* p_ki  = (const float*)d_in[7];
    const float* p_ke  = (const float*)d_in[8];
    const float* p_dv  = (const float*)d_in[9];
    const float* p_di  = (const float*)d_in[10];
    const float* p_L   = (const float*)d_in[11];

    const int N = in_sizes[0];  // 8*1024*1024 elements

    float* out     = (float*)d_out;
    float* cv_new  = out;
    float* ci_new  = out + N;
    float* eta_new = out + 2 * N;

    const dim3 block(256);
    const dim3 grid(1024 / TX, 1024 / TY, N / HW);  // (16, 64, 8)

    irr_fused<<<grid, block, 0, stream>>>(cv, ci, eta, p_ev, p_ei, p_kbt,
                                          p_kv, p_ki, p_ke, p_dv, p_di, p_L,
                                          cv_new, ci_new, eta_new);
}